// Round 6
// baseline (433.031 us; speedup 1.0000x reference)
//
#include <hip/hip_runtime.h>
#include <math.h>

#define G_    64
#define NPG_  1600
#define N_    (G_*NPG_)     // 102400
#define EPG_  51200
#define E_    (G_*EPG_)     // 3276800
#define FIN_  512
#define HOUT_ 512
#define KEEP_ 1280

// ---------------------------------------------------------------------------
// K1: per-graph CSR build.  LDS degree hist -> shuffle scan -> LDS-cursor
// scatter INTO LDS (csrs), then coalesced uint4 copy-out.
// ---------------------------------------------------------------------------
__global__ __launch_bounds__(1024) void k_build(const int* __restrict__ esrc,
                                                const int* __restrict__ edst,
                                                int* __restrict__ offs,
                                                int* __restrict__ rend,
                                                float* __restrict__ dis,
                                                unsigned short* __restrict__ csr) {
  __shared__ __align__(16) unsigned short csrs[EPG_];   // 102,400 B
  __shared__ int hist[NPG_];                            // 6,400 B
  __shared__ int wsum[16];
  const int g = blockIdx.x, t = threadIdx.x;
  const int lane = t & 63, wid = t >> 6;
  const int eb = g * EPG_, nb = g * NPG_;

  for (int i = t; i < NPG_; i += 1024) hist[i] = 0;
  __syncthreads();
  for (int e = t; e < EPG_; e += 1024) atomicAdd(&hist[edst[eb + e] - nb], 1);
  __syncthreads();

  int c0 = 0, c1 = 0;
  if (t < 800) { c0 = hist[2 * t]; c1 = hist[2 * t + 1]; }
  const int val = c0 + c1;
  int incl = val;
#pragma unroll
  for (int m = 1; m < 64; m <<= 1) {
    const int u = __shfl_up(incl, m);
    if (lane >= m) incl += u;
  }
  if (lane == 63) wsum[wid] = incl;
  __syncthreads();
  int woff = 0;
  for (int w2 = 0; w2 < wid; ++w2) woff += wsum[w2];
  incl += woff;
  if (t < 800) {
    const int excl = incl - val;          // LOCAL edge offset
    const int p0 = excl, p1 = p0 + c0;
    offs[nb + 2 * t] = eb + p0;     rend[nb + 2 * t] = eb + p1;
    offs[nb + 2 * t + 1] = eb + p1; rend[nb + 2 * t + 1] = eb + p1 + c1;
    dis[nb + 2 * t] = rsqrtf((float)c0 + 1.0f);
    dis[nb + 2 * t + 1] = rsqrtf((float)c1 + 1.0f);
    hist[2 * t] = p0;          // reuse as LOCAL cursor
    hist[2 * t + 1] = p1;
  }
  __syncthreads();
  for (int e = t; e < EPG_; e += 1024) {
    const int s = esrc[eb + e];
    const int d = edst[eb + e] - nb;
    const int p = atomicAdd(&hist[d], 1);
    csrs[p] = (unsigned short)(s - nb);
  }
  __syncthreads();
  // coalesced copy-out: 6400 x uint4 (8 u16 each)
  const uint4* s4 = reinterpret_cast<const uint4*>(csrs);
  uint4* d4 = reinterpret_cast<uint4*>(csr + eb);
  for (int i = t; i < EPG_ / 8; i += 1024) d4[i] = s4[i];
}

// ---------------------------------------------------------------------------
// K2: hd[r] = (x[r] @ W1) * dis[r].  k-SPLIT-4: 4 threads per row.
// Root cause across all prior variants: Occupancy 16-18% (1.3 waves/SIMD) --
// 1 thread/row caps the kernel at 1600-3200 waves; nothing hides latency.
// Now: 409600 threads = 6400 waves = 25/CU (16 resident by 33KB LDS = 4/SIMD).
// Lane l: q = l&3 (k-quarter), rows rb+(l>>2) and rb+(l>>2)+16 (2 rows/lane
// so each staged weight chunk feeds 128 FMAs).  W1 in LDS with quarter
// stagger (q*2052 words; 2052 mod 32 = 4) -> the wave's 4 broadcast address
// groups hit disjoint bank quads -> conflict-free.  2-step shfl_xor reduce
// over the q bits; static-select write; stores perfectly coalesced.
// ---------------------------------------------------------------------------
#define WQ_ 2052   // staggered quarter stride in floats (513 float4)
__global__ __launch_bounds__(256, 2) void k_xw1(const float* __restrict__ x,
                                                const float* __restrict__ W1,
                                                const float* __restrict__ dis,
                                                float* __restrict__ hd) {
  __shared__ __align__(16) float wl[4 * WQ_];     // 32,832 B
  const int t = threadIdx.x;
  const int lane = t & 63, wid = t >> 6;
  const int q = lane & 3;

  {  // stage W1 (2048 float4) with quarter stagger: dest f4 idx = q*513 + m
    const float4* wg = reinterpret_cast<const float4*>(W1);
    float4* wd = reinterpret_cast<float4*>(wl);
    for (int i = t; i < 2048; i += 256) {
      const int qq = i >> 9, m = i & 511;
      wd[qq * 513 + m] = wg[i];
    }
  }
  __syncthreads();

  const int rb = blockIdx.x * 128 + wid * 32;     // grid 800; 32 rows/wave
  const int ra = rb + (lane >> 2);                // row A
  const int rc = ra + 16;                         // row B
  const float4* xg = reinterpret_cast<const float4*>(x);
  const size_t ba = (size_t)ra * 128 + q * 32;    // float4 index bases
  const size_t bb = (size_t)rc * 128 + q * 32;
  const float4* w4 = reinterpret_cast<const float4*>(wl + q * WQ_);

  float acc_a[16], acc_b[16];
#pragma unroll
  for (int j = 0; j < 16; ++j) { acc_a[j] = 0.f; acc_b[j] = 0.f; }

  float4 xa = xg[ba];
  float4 xb = xg[bb];
#pragma unroll 2
  for (int i = 0; i < 32; ++i) {
    const int in = (i < 31) ? i + 1 : 31;
    float4 na = xg[ba + in];                      // prefetch next i
    float4 nb = xg[bb + in];
    const float xsa[4] = {xa.x, xa.y, xa.z, xa.w};
    const float xsb[4] = {xb.x, xb.y, xb.z, xb.w};
#pragma unroll
    for (int kk = 0; kk < 4; ++kk) {
      const float a = xsa[kk], b = xsb[kk];
#pragma unroll
      for (int c = 0; c < 4; ++c) {
        const float4 wv = w4[i * 16 + kk * 4 + c];
        acc_a[c * 4 + 0] = fmaf(a, wv.x, acc_a[c * 4 + 0]);
        acc_a[c * 4 + 1] = fmaf(a, wv.y, acc_a[c * 4 + 1]);
        acc_a[c * 4 + 2] = fmaf(a, wv.z, acc_a[c * 4 + 2]);
        acc_a[c * 4 + 3] = fmaf(a, wv.w, acc_a[c * 4 + 3]);
        acc_b[c * 4 + 0] = fmaf(b, wv.x, acc_b[c * 4 + 0]);
        acc_b[c * 4 + 1] = fmaf(b, wv.y, acc_b[c * 4 + 1]);
        acc_b[c * 4 + 2] = fmaf(b, wv.z, acc_b[c * 4 + 2]);
        acc_b[c * 4 + 3] = fmaf(b, wv.w, acc_b[c * 4 + 3]);
      }
    }
    xa = na; xb = nb;
  }

  // reduce over the 4 k-quarters (lane bits 0-1)
#pragma unroll
  for (int m = 1; m < 4; m <<= 1)
#pragma unroll
    for (int j = 0; j < 16; ++j) {
      acc_a[j] += __shfl_xor(acc_a[j], m);
      acc_b[j] += __shfl_xor(acc_b[j], m);
    }

  // lane q writes float4 #q of each row (static-index select)
  float4 oa, ob;
  if (q == 0) {
    oa = make_float4(acc_a[0], acc_a[1], acc_a[2], acc_a[3]);
    ob = make_float4(acc_b[0], acc_b[1], acc_b[2], acc_b[3]);
  } else if (q == 1) {
    oa = make_float4(acc_a[4], acc_a[5], acc_a[6], acc_a[7]);
    ob = make_float4(acc_b[4], acc_b[5], acc_b[6], acc_b[7]);
  } else if (q == 2) {
    oa = make_float4(acc_a[8], acc_a[9], acc_a[10], acc_a[11]);
    ob = make_float4(acc_b[8], acc_b[9], acc_b[10], acc_b[11]);
  } else {
    oa = make_float4(acc_a[12], acc_a[13], acc_a[14], acc_a[15]);
    ob = make_float4(acc_b[12], acc_b[13], acc_b[14], acc_b[15]);
  }
  const float da = dis[ra], db = dis[rc];
  float4* hd4 = reinterpret_cast<float4*>(hd);
  hd4[(size_t)ra * 4 + q] = make_float4(oa.x * da, oa.y * da, oa.z * da, oa.w * da);
  hd4[(size_t)rc * 4 + q] = make_float4(ob.x * db, ob.y * db, ob.z * db, ob.w * db);
}

// ---------------------------------------------------------------------------
// K3: conv1 gather, LDS-staged (per-graph hd slice = 102.4 KB in LDS).
// ---------------------------------------------------------------------------
__global__ __launch_bounds__(1024) void k_conv1l(
    const unsigned short* __restrict__ csr, const int* __restrict__ offs,
    const int* __restrict__ rend, const float* __restrict__ hd,
    const float* __restrict__ dis, const float* __restrict__ b1,
    const float* __restrict__ Wrel, const float* __restrict__ Wroot,
    float* __restrict__ h1, float* __restrict__ rarr, float* __restrict__ tarr) {
  __shared__ float hds[NPG_ * 16];                // 102,400 B
  const int g = blockIdx.x >> 2, q = blockIdx.x & 3;
  const int nb = g * NPG_;
  const int t = threadIdx.x;
  {
    const float4* src = reinterpret_cast<const float4*>(hd + (size_t)nb * 16);
    float4* dst = reinterpret_cast<float4*>(hds);
    for (int i = t; i < NPG_ * 4; i += 1024) dst[i] = src[i];
  }
  __syncthreads();
  const int c = t & 15;
  const float bb = b1[c], wr = Wrel[c], wo = Wroot[c];
  const int vend = q * 400 + 400;
  for (int vl = q * 400 + (t >> 4); vl < vend; vl += 64) {
    const int v = nb + vl;
    const int rs = offs[v], re = rend[v];
    float acc = 0.f;
    int k = rs;
    for (; k + 4 <= re; k += 4) {
      const int s0 = csr[k], s1 = csr[k + 1];
      const int s2 = csr[k + 2], s3 = csr[k + 3];
      acc += hds[s0 * 16 + c] + hds[s1 * 16 + c];
      acc += hds[s2 * 16 + c] + hds[s3 * 16 + c];
    }
    for (; k < re; ++k) acc += hds[csr[k] * 16 + c];
    const float dd = dis[v];
    float val = fmaf(acc + hds[vl * 16 + c], dd, bb);
    val = fmaxf(val, 0.f);
    h1[(size_t)v * 16 + c] = val;
    float r = val * wr;
    float tt = val * wo;
#pragma unroll
    for (int m = 1; m < 16; m <<= 1) {
      r += __shfl_xor(r, m);
      tt += __shfl_xor(tt, m);
    }
    if (c == 0) { rarr[v] = r; tarr[v] = tt; }
  }
}

// ---------------------------------------------------------------------------
// K4: per-graph fused score + radix-select top-K + filtered degree + h1w.
// Scans are shuffle-based.
// ---------------------------------------------------------------------------
__global__ __launch_bounds__(1024) void k_scoretopk(
    const unsigned short* __restrict__ csr, const int* __restrict__ offs,
    const int* __restrict__ rend, const float* __restrict__ rarr,
    const float* __restrict__ tarr, const float* __restrict__ brel,
    const float* __restrict__ h1, int* __restrict__ kept,
    float* __restrict__ dis2, float* __restrict__ h1w,
    float* __restrict__ out) {
  __shared__ float rar[NPG_];
  __shared__ float sar[NPG_];       // tarr, then score
  __shared__ int   ofs[NPG_];
  __shared__ int   ren[NPG_];
  __shared__ unsigned uu[NPG_];     // monotone keys
  __shared__ int   kp[NPG_];
  __shared__ float wv[NPG_];
  __shared__ int   hist[256];
  __shared__ int   part[16];        // per-wave scan sums
  __shared__ int   scal[2];         // lo, rem

  const int g = blockIdx.x, t = threadIdx.x;
  const int lane = t & 63, wid = t >> 6;
  const int nb = g * NPG_;

  // P0: stage
  for (int i = t; i < NPG_; i += 1024) {
    rar[i] = rarr[nb + i];
    sar[i] = tarr[nb + i];
    ofs[i] = offs[nb + i];
    ren[i] = rend[nb + i];
  }
  if (t == 0) { scal[0] = 0; scal[1] = KEEP_; }
  __syncthreads();

  // P1: score = tanh(sum rar[neighbors] + brel + tarr)
  const float br = brel[0];
  for (int v = t; v < NPG_; v += 1024) {
    const int rs = ofs[v], re = ren[v];
    float sum = 0.f;
    int k = rs;
    for (; k + 4 <= re; k += 4) {
      sum += rar[csr[k]] + rar[csr[k + 1]];
      sum += rar[csr[k + 2]] + rar[csr[k + 3]];
    }
    for (; k < re; ++k) sum += rar[csr[k]];
    const float s = tanhf(sum + br + sar[v]);
    sar[v] = s;
    const unsigned ub = __float_as_uint(s);
    uu[v] = (ub & 0x80000000u) ? ~ub : (ub | 0x80000000u);
  }
  __syncthreads();

  // P2: radix select (4 passes of 8 bits, MSB first)
  const unsigned maskTab[4] = {0u, 0xFF000000u, 0xFFFF0000u, 0xFFFFFF00u};
  const int shTab[4] = {24, 16, 8, 0};
  for (int pass = 0; pass < 4; ++pass) {
    const unsigned lo = (unsigned)scal[0];
    const int remc = scal[1];
    const unsigned msk = maskTab[pass];
    const int sh = shTab[pass];
    if (t < 256) hist[t] = 0;
    __syncthreads();
    for (int v = t; v < NPG_; v += 1024) {
      const unsigned u = uu[v];
      if (((u ^ lo) & msk) == 0) atomicAdd(&hist[(u >> sh) & 255], 1);
    }
    __syncthreads();
    int hv = 0;
    if (t < 256) hv = hist[t];
    int incl = hv;
#pragma unroll
    for (int m = 1; m < 64; m <<= 1) {
      const int u2 = __shfl_up(incl, m);
      if (lane >= m) incl += u2;
    }
    if (t < 256 && lane == 63) part[wid] = incl;  // waves 0..3
    __syncthreads();
    if (t < 256) {
      int woff = 0;
      for (int w2 = 0; w2 < wid; ++w2) woff += part[w2];
      const int tot = part[0] + part[1] + part[2] + part[3];
      const int sb = tot - (incl + woff) + hv;    // suffix sum from bin t
      const int sb1 = sb - hv;                    // suffix sum from bin t+1
      if (sb >= remc && sb1 < remc) {             // unique boundary bin
        scal[0] = (int)(lo | ((unsigned)t << sh));
        scal[1] = remc - sb1;
      }
    }
    __syncthreads();
  }
  const unsigned T = (unsigned)scal[0];
  const int remT = scal[1];

  // tie-break by index: keep first remT nodes with key == T (shuffle scan)
  const int i0 = 2 * t, i1 = 2 * t + 1;
  int f0 = 0, f1 = 0;
  if (i0 < NPG_) f0 = (uu[i0] == T);
  if (i1 < NPG_) f1 = (uu[i1] == T);
  int incl2 = f0 + f1;
#pragma unroll
  for (int m = 1; m < 64; m <<= 1) {
    const int u2 = __shfl_up(incl2, m);
    if (lane >= m) incl2 += u2;
  }
  if (lane == 63) part[wid] = incl2;
  __syncthreads();
  int woff2 = 0;
  for (int w2 = 0; w2 < wid; ++w2) woff2 += part[w2];
  const int excl = incl2 + woff2 - (f0 + f1);
  if (i0 < NPG_) kp[i0] = (uu[i0] > T) || (f0 && excl < remT);
  if (i1 < NPG_) kp[i1] = (uu[i1] > T) || (f1 && (excl + f0) < remT);
  __syncthreads();
  for (int v = t; v < NPG_; v += 1024) kept[nb + v] = kp[v];

  // P3: filtered degree -> dis2, wv = score * dis2 (0 for dropped)
  for (int v = t; v < NPG_; v += 1024) {
    float w = 0.f;
    if (kp[v]) {
      const int rs = ofs[v], re = ren[v];
      int c2 = 0, k = rs;
      for (; k + 4 <= re; k += 4) {
        c2 += kp[csr[k]] + kp[csr[k + 1]];
        c2 += kp[csr[k + 2]] + kp[csr[k + 3]];
      }
      for (; k < re; ++k) c2 += kp[csr[k]];
      const float d2 = rsqrtf((float)c2 + 1.0f);
      dis2[nb + v] = d2;
      w = sar[v] * d2;
    }
    wv[v] = w;
  }
  // zero the output slice for this graph
  if (t < HOUT_) out[g * HOUT_ + t] = 0.f;
  __syncthreads();

  // P4: h1w = h1 * wv[v]
  for (int i = t; i < NPG_ * 16; i += 1024)
    h1w[(size_t)nb * 16 + i] = h1[(size_t)nb * 16 + i] * wv[i >> 4];
}

// ---------------------------------------------------------------------------
// K5: conv2 gather, LDS-staged (same structure as K3).
// ---------------------------------------------------------------------------
__global__ __launch_bounds__(1024) void k_conv2l(
    const unsigned short* __restrict__ csr, const int* __restrict__ offs,
    const int* __restrict__ rend, const float* __restrict__ h1w,
    const int* __restrict__ kept, const float* __restrict__ dis2,
    float* __restrict__ y16) {
  __shared__ float hds[NPG_ * 16];                // 102,400 B
  const int g = blockIdx.x >> 2, q = blockIdx.x & 3;
  const int nb = g * NPG_;
  const int t = threadIdx.x;
  {
    const float4* src = reinterpret_cast<const float4*>(h1w + (size_t)nb * 16);
    float4* dst = reinterpret_cast<float4*>(hds);
    for (int i = t; i < NPG_ * 4; i += 1024) dst[i] = src[i];
  }
  __syncthreads();
  const int c = t & 15;
  const int vend = q * 400 + 400;
  for (int vl = q * 400 + (t >> 4); vl < vend; vl += 64) {
    const int v = nb + vl;
    if (!kept[v]) continue;                       // uniform per 16-group
    const int rs = offs[v], re = rend[v];
    float acc = 0.f;
    int k = rs;
    for (; k + 4 <= re; k += 4) {
      const int s0 = csr[k], s1 = csr[k + 1];
      const int s2 = csr[k + 2], s3 = csr[k + 3];
      acc += hds[s0 * 16 + c] + hds[s1 * 16 + c];
      acc += hds[s2 * 16 + c] + hds[s3 * 16 + c];
    }
    for (; k < re; ++k) acc += hds[csr[k] * 16 + c];
    acc += hds[vl * 16 + c];                      // self loop
    y16[(size_t)v * 16 + c] = acc * dis2[v];
  }
}

// ---------------------------------------------------------------------------
// K6: out[g] += relu(y16[v]@W2 + b2)/K  fused GEMM+ReLU+mean-pool.
// ---------------------------------------------------------------------------
__global__ __launch_bounds__(256, 1) void k_gemm2pool(const float* __restrict__ y16,
                                                      const int* __restrict__ kept,
                                                      const float* __restrict__ W2,
                                                      const float* __restrict__ b2,
                                                      float* __restrict__ out) {
  __shared__ float red[256];
  const int blk = blockIdx.x;                     // grid 2048
  const int g = blk >> 5;
  const int sub = blk & 31;
  const int jbase = (sub & 1) * 256;
  const int nstart = g * NPG_ + (sub >> 1) * 100;
  const int tid = threadIdx.x;
  const int wave = tid >> 6, lane = tid & 63;

  float w[16][4];
#pragma unroll
  for (int k = 0; k < 16; ++k)
#pragma unroll
    for (int c = 0; c < 4; ++c)
      w[k][c] = W2[k * HOUT_ + jbase + lane + c * 64];
  float b2r[4];
#pragma unroll
  for (int c = 0; c < 4; ++c) b2r[c] = b2[jbase + lane + c * 64];

  float acc[4] = {0.f, 0.f, 0.f, 0.f};
  for (int i = wave; i < 100; i += 4) {
    const int v = nstart + i;
    if (!kept[v]) continue;                       // wave-uniform
    const float4* yp = reinterpret_cast<const float4*>(y16 + (size_t)v * 16);
    float4 q0 = yp[0], q1 = yp[1], q2 = yp[2], q3 = yp[3];
    const float yv[16] = {q0.x, q0.y, q0.z, q0.w, q1.x, q1.y, q1.z, q1.w,
                          q2.x, q2.y, q2.z, q2.w, q3.x, q3.y, q3.z, q3.w};
    float z[4] = {b2r[0], b2r[1], b2r[2], b2r[3]};
#pragma unroll
    for (int k = 0; k < 16; ++k)
#pragma unroll
      for (int c = 0; c < 4; ++c)
        z[c] = fmaf(yv[k], w[k][c], z[c]);
#pragma unroll
    for (int c = 0; c < 4; ++c) acc[c] += fmaxf(z[c], 0.f);
  }

  red[tid] = 0.f;
  __syncthreads();
#pragma unroll
  for (int c = 0; c < 4; ++c) atomicAdd(&red[lane + 64 * c], acc[c]);
  __syncthreads();
  atomicAdd(&out[g * HOUT_ + jbase + tid], red[tid] * (1.0f / (float)KEEP_));
}

// ---------------------------------------------------------------------------
extern "C" void kernel_launch(void* const* d_in, const int* in_sizes, int n_in,
                              void* d_out, int out_size, void* d_ws, size_t ws_size,
                              hipStream_t stream) {
  (void)in_sizes; (void)n_in; (void)out_size; (void)ws_size;
  const float* x     = (const float*)d_in[0];
  const int*   ei    = (const int*)  d_in[1];
  const float* W1    = (const float*)d_in[3];
  const float* b1    = (const float*)d_in[4];
  const float* Wrel  = (const float*)d_in[5];
  const float* brel  = (const float*)d_in[6];
  const float* Wroot = (const float*)d_in[7];
  const float* W2    = (const float*)d_in[8];
  const float* b2    = (const float*)d_in[9];
  const int* esrc = ei;
  const int* edst = ei + E_;

  // slab quarters: hd / h1 / h1w / y16
  char* ws = (char*)d_ws;
  float*          hd    = (float*)(ws);                    // q0: 6,553,600 B
  float*          h1    = (float*)(ws + 6553600);          // q1
  float*          h1w   = (float*)(ws + 13107200);         // q2
  float*          y16   = (float*)(ws + 19660800);         // q3
  unsigned short* csr   = (unsigned short*)(ws + 26214400);// 6,553,600 B
  int*            offs  = (int*)(ws + 32768000);
  int*            rendp = (int*)(ws + 33177600);
  float*          dis   = (float*)(ws + 33587200);
  int*            kept  = (int*)(ws + 33996800);
  float*          rarr  = (float*)(ws + 34406400);
  float*          tarr  = (float*)(ws + 34816000);
  float*          dis2  = (float*)(ws + 35225600);
  float*          out   = (float*)d_out;

  hipLaunchKernelGGL(k_build,     dim3(G_),    dim3(1024), 0, stream,
                     esrc, edst, offs, rendp, dis, csr);
  hipLaunchKernelGGL(k_xw1,       dim3(800),   dim3(256),  0, stream,
                     x, W1, dis, hd);
  hipLaunchKernelGGL(k_conv1l,    dim3(256),   dim3(1024), 0, stream,
                     csr, offs, rendp, hd, dis, b1, Wrel, Wroot, h1, rarr, tarr);
  hipLaunchKernelGGL(k_scoretopk, dim3(G_),    dim3(1024), 0, stream,
                     csr, offs, rendp, rarr, tarr, brel, h1, kept, dis2, h1w, out);
  hipLaunchKernelGGL(k_conv2l,    dim3(256),   dim3(1024), 0, stream,
                     csr, offs, rendp, h1w, kept, dis2, y16);
  hipLaunchKernelGGL(k_gemm2pool, dim3(2048),  dim3(256),  0, stream,
                     y16, kept, W2, b2, out);
}

// Round 7
// 237.477 us; speedup vs baseline: 1.8235x; 1.8235x over previous
//
#include <hip/hip_runtime.h>
#include <math.h>

#define G_    64
#define NPG_  1600
#define N_    (G_*NPG_)     // 102400
#define EPG_  51200
#define E_    (G_*EPG_)     // 3276800
#define FIN_  512
#define HOUT_ 512
#define KEEP_ 1280

// ---------------------------------------------------------------------------
// K1: per-graph CSR build.  LDS degree hist -> shuffle scan -> LDS-cursor
// scatter INTO LDS (csrs), then coalesced uint4 copy-out.
// ---------------------------------------------------------------------------
__global__ __launch_bounds__(1024) void k_build(const int* __restrict__ esrc,
                                                const int* __restrict__ edst,
                                                int* __restrict__ offs,
                                                int* __restrict__ rend,
                                                float* __restrict__ dis,
                                                unsigned short* __restrict__ csr) {
  __shared__ __align__(16) unsigned short csrs[EPG_];   // 102,400 B
  __shared__ int hist[NPG_];                            // 6,400 B
  __shared__ int wsum[16];
  const int g = blockIdx.x, t = threadIdx.x;
  const int lane = t & 63, wid = t >> 6;
  const int eb = g * EPG_, nb = g * NPG_;

  for (int i = t; i < NPG_; i += 1024) hist[i] = 0;
  __syncthreads();
  for (int e = t; e < EPG_; e += 1024) atomicAdd(&hist[edst[eb + e] - nb], 1);
  __syncthreads();

  int c0 = 0, c1 = 0;
  if (t < 800) { c0 = hist[2 * t]; c1 = hist[2 * t + 1]; }
  const int val = c0 + c1;
  int incl = val;
#pragma unroll
  for (int m = 1; m < 64; m <<= 1) {
    const int u = __shfl_up(incl, m);
    if (lane >= m) incl += u;
  }
  if (lane == 63) wsum[wid] = incl;
  __syncthreads();
  int woff = 0;
  for (int w2 = 0; w2 < wid; ++w2) woff += wsum[w2];
  incl += woff;
  if (t < 800) {
    const int excl = incl - val;          // LOCAL edge offset
    const int p0 = excl, p1 = p0 + c0;
    offs[nb + 2 * t] = eb + p0;     rend[nb + 2 * t] = eb + p1;
    offs[nb + 2 * t + 1] = eb + p1; rend[nb + 2 * t + 1] = eb + p1 + c1;
    dis[nb + 2 * t] = rsqrtf((float)c0 + 1.0f);
    dis[nb + 2 * t + 1] = rsqrtf((float)c1 + 1.0f);
    hist[2 * t] = p0;          // reuse as LOCAL cursor
    hist[2 * t + 1] = p1;
  }
  __syncthreads();
  for (int e = t; e < EPG_; e += 1024) {
    const int s = esrc[eb + e];
    const int d = edst[eb + e] - nb;
    const int p = atomicAdd(&hist[d], 1);
    csrs[p] = (unsigned short)(s - nb);
  }
  __syncthreads();
  // coalesced copy-out: 6400 x uint4 (8 u16 each)
  const uint4* s4 = reinterpret_cast<const uint4*>(csrs);
  uint4* d4 = reinterpret_cast<uint4*>(csr + eb);
  for (int i = t; i < EPG_ / 8; i += 1024) d4[i] = s4[i];
}

// ---------------------------------------------------------------------------
// K2: hd[r] = (x[r] @ W1) * dis[r].  WHOLE-WAVE-PER-ROW, W1 IN REGISTERS.
// Round-6 lesson: per-lane-strided x reads amplify 4x per line; at high
// occupancy L1 thrashes -> FETCH 793MB.  So x loads MUST be wave-contiguous:
// lane l reads float4 #l and #(64+l) of the row -> 2 x 1KB coalesced loads,
// zero amplification.  W1 slice (lane owns k rows 4l..4l+3, 256+4l..+3) =
// 32 float4 in VGPRs, staged once (round-5's spill fixed: launch_bounds
// (256,1) lifts the 96-VGPR cap; expect ~190 VGPR, 2 waves/SIMD, ZERO LDS).
// Reduction = reduce-scatter tree (17 shfl instead of 96): at step s lane
// keeps the acc-half matching its lane-bit s -> lane l ends with the full
// sum for j = l&15; one 256B coalesced store per 4 rows.
// ---------------------------------------------------------------------------
__global__ __launch_bounds__(256, 1) void k_xw1(const float* __restrict__ x,
                                                const float* __restrict__ W1,
                                                const float* __restrict__ dis,
                                                float* __restrict__ hd) {
  const int t = threadIdx.x;
  const int lane = t & 63, wid = t >> 6;

  // stage W1 k-slice into registers: wq[kk*4+c] = W1 row (4l+kk | 256+4l+kk-16?),
  // kk 0..3 -> k = 4*lane+kk ; kk 4..7 -> k = 256+4*lane+(kk-4); c = j-quad.
  float4 wq[32];
  {
    const float4* wg = reinterpret_cast<const float4*>(W1);
#pragma unroll
    for (int kk = 0; kk < 4; ++kk)
#pragma unroll
      for (int c = 0; c < 4; ++c)
        wq[kk * 4 + c] = wg[(4 * lane + kk) * 4 + c];
#pragma unroll
    for (int kk = 0; kk < 4; ++kk)
#pragma unroll
      for (int c = 0; c < 4; ++c)
        wq[(4 + kk) * 4 + c] = wg[(256 + 4 * lane + kk) * 4 + c];
  }

  const int rb = blockIdx.x * 128 + wid * 32;     // grid 800, 32 rows/wave
  const float4* xg = reinterpret_cast<const float4*>(x);
  const int b0 = lane & 1, b1 = (lane >> 1) & 1, b2 = (lane >> 2) & 1,
            b3 = (lane >> 3) & 1;

  float4 xa = xg[(size_t)rb * 128 + lane];        // current row halves
  float4 xb = xg[(size_t)rb * 128 + 64 + lane];

  for (int rg = 0; rg < 32; rg += 4) {
    float o0 = 0.f, o1 = 0.f, o2 = 0.f, o3 = 0.f;
#pragma unroll
    for (int m = 0; m < 4; ++m) {
      const int r = rb + rg + m;
      const int rn = (rg + m < 31) ? r + 1 : r;   // prefetch next row
      float4 na = xg[(size_t)rn * 128 + lane];
      float4 nb = xg[(size_t)rn * 128 + 64 + lane];

      float acc[16];
#pragma unroll
      for (int j = 0; j < 16; ++j) acc[j] = 0.f;
      const float xs[8] = {xa.x, xa.y, xa.z, xa.w, xb.x, xb.y, xb.z, xb.w};
#pragma unroll
      for (int kk = 0; kk < 8; ++kk)
#pragma unroll
        for (int c = 0; c < 4; ++c) {
          const float4 wv = wq[kk * 4 + c];
          acc[c * 4 + 0] = fmaf(xs[kk], wv.x, acc[c * 4 + 0]);
          acc[c * 4 + 1] = fmaf(xs[kk], wv.y, acc[c * 4 + 1]);
          acc[c * 4 + 2] = fmaf(xs[kk], wv.z, acc[c * 4 + 2]);
          acc[c * 4 + 3] = fmaf(xs[kk], wv.w, acc[c * 4 + 3]);
        }

      // reduce-scatter: lane ends with full sum for j = lane&15
      float a8[8];
#pragma unroll
      for (int u = 0; u < 8; ++u) {
        const float keep = b0 ? acc[2 * u + 1] : acc[2 * u];
        const float send = b0 ? acc[2 * u] : acc[2 * u + 1];
        a8[u] = keep + __shfl_xor(send, 1);
      }
      float a4[4];
#pragma unroll
      for (int u = 0; u < 4; ++u) {
        const float keep = b1 ? a8[2 * u + 1] : a8[2 * u];
        const float send = b1 ? a8[2 * u] : a8[2 * u + 1];
        a4[u] = keep + __shfl_xor(send, 2);
      }
      float a2[2];
#pragma unroll
      for (int u = 0; u < 2; ++u) {
        const float keep = b2 ? a4[2 * u + 1] : a4[2 * u];
        const float send = b2 ? a4[2 * u] : a4[2 * u + 1];
        a2[u] = keep + __shfl_xor(send, 4);
      }
      float a1;
      {
        const float keep = b3 ? a2[1] : a2[0];
        const float send = b3 ? a2[0] : a2[1];
        a1 = keep + __shfl_xor(send, 8);
      }
      a1 += __shfl_xor(a1, 16);
      a1 += __shfl_xor(a1, 32);

      const float vv = a1 * dis[r];
      if (m == 0) o0 = vv;
      else if (m == 1) o1 = vv;
      else if (m == 2) o2 = vv;
      else o3 = vv;
      xa = na; xb = nb;
    }
    // coalesced 256B store: lane l writes row rb+rg+(l>>4), elem l&15
    const int rs = lane >> 4;
    const float ov = (rs == 0) ? o0 : (rs == 1) ? o1 : (rs == 2) ? o2 : o3;
    hd[(size_t)(rb + rg + rs) * 16 + (lane & 15)] = ov;
  }
}

// ---------------------------------------------------------------------------
// K3: conv1 gather, LDS-staged (per-graph hd slice = 102.4 KB in LDS).
// ---------------------------------------------------------------------------
__global__ __launch_bounds__(1024) void k_conv1l(
    const unsigned short* __restrict__ csr, const int* __restrict__ offs,
    const int* __restrict__ rend, const float* __restrict__ hd,
    const float* __restrict__ dis, const float* __restrict__ b1,
    const float* __restrict__ Wrel, const float* __restrict__ Wroot,
    float* __restrict__ h1, float* __restrict__ rarr, float* __restrict__ tarr) {
  __shared__ float hds[NPG_ * 16];                // 102,400 B
  const int g = blockIdx.x >> 2, q = blockIdx.x & 3;
  const int nb = g * NPG_;
  const int t = threadIdx.x;
  {
    const float4* src = reinterpret_cast<const float4*>(hd + (size_t)nb * 16);
    float4* dst = reinterpret_cast<float4*>(hds);
    for (int i = t; i < NPG_ * 4; i += 1024) dst[i] = src[i];
  }
  __syncthreads();
  const int c = t & 15;
  const float bb = b1[c], wr = Wrel[c], wo = Wroot[c];
  const int vend = q * 400 + 400;
  for (int vl = q * 400 + (t >> 4); vl < vend; vl += 64) {
    const int v = nb + vl;
    const int rs = offs[v], re = rend[v];
    float acc = 0.f;
    int k = rs;
    for (; k + 4 <= re; k += 4) {
      const int s0 = csr[k], s1 = csr[k + 1];
      const int s2 = csr[k + 2], s3 = csr[k + 3];
      acc += hds[s0 * 16 + c] + hds[s1 * 16 + c];
      acc += hds[s2 * 16 + c] + hds[s3 * 16 + c];
    }
    for (; k < re; ++k) acc += hds[csr[k] * 16 + c];
    const float dd = dis[v];
    float val = fmaf(acc + hds[vl * 16 + c], dd, bb);
    val = fmaxf(val, 0.f);
    h1[(size_t)v * 16 + c] = val;
    float r = val * wr;
    float tt = val * wo;
#pragma unroll
    for (int m = 1; m < 16; m <<= 1) {
      r += __shfl_xor(r, m);
      tt += __shfl_xor(tt, m);
    }
    if (c == 0) { rarr[v] = r; tarr[v] = tt; }
  }
}

// ---------------------------------------------------------------------------
// K4: per-graph fused score + radix-select top-K + filtered degree + h1w.
// Scans are shuffle-based.
// ---------------------------------------------------------------------------
__global__ __launch_bounds__(1024) void k_scoretopk(
    const unsigned short* __restrict__ csr, const int* __restrict__ offs,
    const int* __restrict__ rend, const float* __restrict__ rarr,
    const float* __restrict__ tarr, const float* __restrict__ brel,
    const float* __restrict__ h1, int* __restrict__ kept,
    float* __restrict__ dis2, float* __restrict__ h1w,
    float* __restrict__ out) {
  __shared__ float rar[NPG_];
  __shared__ float sar[NPG_];       // tarr, then score
  __shared__ int   ofs[NPG_];
  __shared__ int   ren[NPG_];
  __shared__ unsigned uu[NPG_];     // monotone keys
  __shared__ int   kp[NPG_];
  __shared__ float wv[NPG_];
  __shared__ int   hist[256];
  __shared__ int   part[16];        // per-wave scan sums
  __shared__ int   scal[2];         // lo, rem

  const int g = blockIdx.x, t = threadIdx.x;
  const int lane = t & 63, wid = t >> 6;
  const int nb = g * NPG_;

  // P0: stage
  for (int i = t; i < NPG_; i += 1024) {
    rar[i] = rarr[nb + i];
    sar[i] = tarr[nb + i];
    ofs[i] = offs[nb + i];
    ren[i] = rend[nb + i];
  }
  if (t == 0) { scal[0] = 0; scal[1] = KEEP_; }
  __syncthreads();

  // P1: score = tanh(sum rar[neighbors] + brel + tarr)
  const float br = brel[0];
  for (int v = t; v < NPG_; v += 1024) {
    const int rs = ofs[v], re = ren[v];
    float sum = 0.f;
    int k = rs;
    for (; k + 4 <= re; k += 4) {
      sum += rar[csr[k]] + rar[csr[k + 1]];
      sum += rar[csr[k + 2]] + rar[csr[k + 3]];
    }
    for (; k < re; ++k) sum += rar[csr[k]];
    const float s = tanhf(sum + br + sar[v]);
    sar[v] = s;
    const unsigned ub = __float_as_uint(s);
    uu[v] = (ub & 0x80000000u) ? ~ub : (ub | 0x80000000u);
  }
  __syncthreads();

  // P2: radix select (4 passes of 8 bits, MSB first)
  const unsigned maskTab[4] = {0u, 0xFF000000u, 0xFFFF0000u, 0xFFFFFF00u};
  const int shTab[4] = {24, 16, 8, 0};
  for (int pass = 0; pass < 4; ++pass) {
    const unsigned lo = (unsigned)scal[0];
    const int remc = scal[1];
    const unsigned msk = maskTab[pass];
    const int sh = shTab[pass];
    if (t < 256) hist[t] = 0;
    __syncthreads();
    for (int v = t; v < NPG_; v += 1024) {
      const unsigned u = uu[v];
      if (((u ^ lo) & msk) == 0) atomicAdd(&hist[(u >> sh) & 255], 1);
    }
    __syncthreads();
    int hv = 0;
    if (t < 256) hv = hist[t];
    int incl = hv;
#pragma unroll
    for (int m = 1; m < 64; m <<= 1) {
      const int u2 = __shfl_up(incl, m);
      if (lane >= m) incl += u2;
    }
    if (t < 256 && lane == 63) part[wid] = incl;  // waves 0..3
    __syncthreads();
    if (t < 256) {
      int woff = 0;
      for (int w2 = 0; w2 < wid; ++w2) woff += part[w2];
      const int tot = part[0] + part[1] + part[2] + part[3];
      const int sb = tot - (incl + woff) + hv;    // suffix sum from bin t
      const int sb1 = sb - hv;                    // suffix sum from bin t+1
      if (sb >= remc && sb1 < remc) {             // unique boundary bin
        scal[0] = (int)(lo | ((unsigned)t << sh));
        scal[1] = remc - sb1;
      }
    }
    __syncthreads();
  }
  const unsigned T = (unsigned)scal[0];
  const int remT = scal[1];

  // tie-break by index: keep first remT nodes with key == T (shuffle scan)
  const int i0 = 2 * t, i1 = 2 * t + 1;
  int f0 = 0, f1 = 0;
  if (i0 < NPG_) f0 = (uu[i0] == T);
  if (i1 < NPG_) f1 = (uu[i1] == T);
  int incl2 = f0 + f1;
#pragma unroll
  for (int m = 1; m < 64; m <<= 1) {
    const int u2 = __shfl_up(incl2, m);
    if (lane >= m) incl2 += u2;
  }
  if (lane == 63) part[wid] = incl2;
  __syncthreads();
  int woff2 = 0;
  for (int w2 = 0; w2 < wid; ++w2) woff2 += part[w2];
  const int excl = incl2 + woff2 - (f0 + f1);
  if (i0 < NPG_) kp[i0] = (uu[i0] > T) || (f0 && excl < remT);
  if (i1 < NPG_) kp[i1] = (uu[i1] > T) || (f1 && (excl + f0) < remT);
  __syncthreads();
  for (int v = t; v < NPG_; v += 1024) kept[nb + v] = kp[v];

  // P3: filtered degree -> dis2, wv = score * dis2 (0 for dropped)
  for (int v = t; v < NPG_; v += 1024) {
    float w = 0.f;
    if (kp[v]) {
      const int rs = ofs[v], re = ren[v];
      int c2 = 0, k = rs;
      for (; k + 4 <= re; k += 4) {
        c2 += kp[csr[k]] + kp[csr[k + 1]];
        c2 += kp[csr[k + 2]] + kp[csr[k + 3]];
      }
      for (; k < re; ++k) c2 += kp[csr[k]];
      const float d2 = rsqrtf((float)c2 + 1.0f);
      dis2[nb + v] = d2;
      w = sar[v] * d2;
    }
    wv[v] = w;
  }
  // zero the output slice for this graph
  if (t < HOUT_) out[g * HOUT_ + t] = 0.f;
  __syncthreads();

  // P4: h1w = h1 * wv[v]
  for (int i = t; i < NPG_ * 16; i += 1024)
    h1w[(size_t)nb * 16 + i] = h1[(size_t)nb * 16 + i] * wv[i >> 4];
}

// ---------------------------------------------------------------------------
// K5: conv2 gather, LDS-staged (same structure as K3).
// ---------------------------------------------------------------------------
__global__ __launch_bounds__(1024) void k_conv2l(
    const unsigned short* __restrict__ csr, const int* __restrict__ offs,
    const int* __restrict__ rend, const float* __restrict__ h1w,
    const int* __restrict__ kept, const float* __restrict__ dis2,
    float* __restrict__ y16) {
  __shared__ float hds[NPG_ * 16];                // 102,400 B
  const int g = blockIdx.x >> 2, q = blockIdx.x & 3;
  const int nb = g * NPG_;
  const int t = threadIdx.x;
  {
    const float4* src = reinterpret_cast<const float4*>(h1w + (size_t)nb * 16);
    float4* dst = reinterpret_cast<float4*>(hds);
    for (int i = t; i < NPG_ * 4; i += 1024) dst[i] = src[i];
  }
  __syncthreads();
  const int c = t & 15;
  const int vend = q * 400 + 400;
  for (int vl = q * 400 + (t >> 4); vl < vend; vl += 64) {
    const int v = nb + vl;
    if (!kept[v]) continue;                       // uniform per 16-group
    const int rs = offs[v], re = rend[v];
    float acc = 0.f;
    int k = rs;
    for (; k + 4 <= re; k += 4) {
      const int s0 = csr[k], s1 = csr[k + 1];
      const int s2 = csr[k + 2], s3 = csr[k + 3];
      acc += hds[s0 * 16 + c] + hds[s1 * 16 + c];
      acc += hds[s2 * 16 + c] + hds[s3 * 16 + c];
    }
    for (; k < re; ++k) acc += hds[csr[k] * 16 + c];
    acc += hds[vl * 16 + c];                      // self loop
    y16[(size_t)v * 16 + c] = acc * dis2[v];
  }
}

// ---------------------------------------------------------------------------
// K6: out[g] += relu(y16[v]@W2 + b2)/K  fused GEMM+ReLU+mean-pool.
// ---------------------------------------------------------------------------
__global__ __launch_bounds__(256, 1) void k_gemm2pool(const float* __restrict__ y16,
                                                      const int* __restrict__ kept,
                                                      const float* __restrict__ W2,
                                                      const float* __restrict__ b2,
                                                      float* __restrict__ out) {
  __shared__ float red[256];
  const int blk = blockIdx.x;                     // grid 2048
  const int g = blk >> 5;
  const int sub = blk & 31;
  const int jbase = (sub & 1) * 256;
  const int nstart = g * NPG_ + (sub >> 1) * 100;
  const int tid = threadIdx.x;
  const int wave = tid >> 6, lane = tid & 63;

  float w[16][4];
#pragma unroll
  for (int k = 0; k < 16; ++k)
#pragma unroll
    for (int c = 0; c < 4; ++c)
      w[k][c] = W2[k * HOUT_ + jbase + lane + c * 64];
  float b2r[4];
#pragma unroll
  for (int c = 0; c < 4; ++c) b2r[c] = b2[jbase + lane + c * 64];

  float acc[4] = {0.f, 0.f, 0.f, 0.f};
  for (int i = wave; i < 100; i += 4) {
    const int v = nstart + i;
    if (!kept[v]) continue;                       // wave-uniform
    const float4* yp = reinterpret_cast<const float4*>(y16 + (size_t)v * 16);
    float4 q0 = yp[0], q1 = yp[1], q2 = yp[2], q3 = yp[3];
    const float yv[16] = {q0.x, q0.y, q0.z, q0.w, q1.x, q1.y, q1.z, q1.w,
                          q2.x, q2.y, q2.z, q2.w, q3.x, q3.y, q3.z, q3.w};
    float z[4] = {b2r[0], b2r[1], b2r[2], b2r[3]};
#pragma unroll
    for (int k = 0; k < 16; ++k)
#pragma unroll
      for (int c = 0; c < 4; ++c)
        z[c] = fmaf(yv[k], w[k][c], z[c]);
#pragma unroll
    for (int c = 0; c < 4; ++c) acc[c] += fmaxf(z[c], 0.f);
  }

  red[tid] = 0.f;
  __syncthreads();
#pragma unroll
  for (int c = 0; c < 4; ++c) atomicAdd(&red[lane + 64 * c], acc[c]);
  __syncthreads();
  atomicAdd(&out[g * HOUT_ + jbase + tid], red[tid] * (1.0f / (float)KEEP_));
}

// ---------------------------------------------------------------------------
extern "C" void kernel_launch(void* const* d_in, const int* in_sizes, int n_in,
                              void* d_out, int out_size, void* d_ws, size_t ws_size,
                              hipStream_t stream) {
  (void)in_sizes; (void)n_in; (void)out_size; (void)ws_size;
  const float* x     = (const float*)d_in[0];
  const int*   ei    = (const int*)  d_in[1];
  const float* W1    = (const float*)d_in[3];
  const float* b1    = (const float*)d_in[4];
  const float* Wrel  = (const float*)d_in[5];
  const float* brel  = (const float*)d_in[6];
  const float* Wroot = (const float*)d_in[7];
  const float* W2    = (const float*)d_in[8];
  const float* b2    = (const float*)d_in[9];
  const int* esrc = ei;
  const int* edst = ei + E_;

  // slab quarters: hd / h1 / h1w / y16
  char* ws = (char*)d_ws;
  float*          hd    = (float*)(ws);                    // q0: 6,553,600 B
  float*          h1    = (float*)(ws + 6553600);          // q1
  float*          h1w   = (float*)(ws + 13107200);         // q2
  float*          y16   = (float*)(ws + 19660800);         // q3
  unsigned short* csr   = (unsigned short*)(ws + 26214400);// 6,553,600 B
  int*            offs  = (int*)(ws + 32768000);
  int*            rendp = (int*)(ws + 33177600);
  float*          dis   = (float*)(ws + 33587200);
  int*            kept  = (int*)(ws + 33996800);
  float*          rarr  = (float*)(ws + 34406400);
  float*          tarr  = (float*)(ws + 34816000);
  float*          dis2  = (float*)(ws + 35225600);
  float*          out   = (float*)d_out;

  hipLaunchKernelGGL(k_build,     dim3(G_),    dim3(1024), 0, stream,
                     esrc, edst, offs, rendp, dis, csr);
  hipLaunchKernelGGL(k_xw1,       dim3(800),   dim3(256),  0, stream,
                     x, W1, dis, hd);
  hipLaunchKernelGGL(k_conv1l,    dim3(256),   dim3(1024), 0, stream,
                     csr, offs, rendp, hd, dis, b1, Wrel, Wroot, h1, rarr, tarr);
  hipLaunchKernelGGL(k_scoretopk, dim3(G_),    dim3(1024), 0, stream,
                     csr, offs, rendp, rarr, tarr, brel, h1, kept, dis2, h1w, out);
  hipLaunchKernelGGL(k_conv2l,    dim3(256),   dim3(1024), 0, stream,
                     csr, offs, rendp, h1w, kept, dis2, y16);
  hipLaunchKernelGGL(k_gemm2pool, dim3(2048),  dim3(256),  0, stream,
                     y16, kept, W2, b2, out);
}

// Round 8
// 222.380 us; speedup vs baseline: 1.9473x; 1.0679x over previous
//
#include <hip/hip_runtime.h>
#include <math.h>

#define G_    64
#define NPG_  1600
#define N_    (G_*NPG_)     // 102400
#define EPG_  51200
#define E_    (G_*EPG_)     // 3276800
#define FIN_  512
#define HOUT_ 512
#define KEEP_ 1280

// ---------------------------------------------------------------------------
// K1: per-graph CSR build.  LDS degree hist -> shuffle scan -> LDS-cursor
// scatter INTO LDS (csrs), then coalesced uint4 copy-out.
// ---------------------------------------------------------------------------
__global__ __launch_bounds__(1024) void k_build(const int* __restrict__ esrc,
                                                const int* __restrict__ edst,
                                                int* __restrict__ offs,
                                                int* __restrict__ rend,
                                                float* __restrict__ dis,
                                                unsigned short* __restrict__ csr) {
  __shared__ __align__(16) unsigned short csrs[EPG_];   // 102,400 B
  __shared__ int hist[NPG_];                            // 6,400 B
  __shared__ int wsum[16];
  const int g = blockIdx.x, t = threadIdx.x;
  const int lane = t & 63, wid = t >> 6;
  const int eb = g * EPG_, nb = g * NPG_;

  for (int i = t; i < NPG_; i += 1024) hist[i] = 0;
  __syncthreads();
  for (int e = t; e < EPG_; e += 1024) atomicAdd(&hist[edst[eb + e] - nb], 1);
  __syncthreads();

  int c0 = 0, c1 = 0;
  if (t < 800) { c0 = hist[2 * t]; c1 = hist[2 * t + 1]; }
  const int val = c0 + c1;
  int incl = val;
#pragma unroll
  for (int m = 1; m < 64; m <<= 1) {
    const int u = __shfl_up(incl, m);
    if (lane >= m) incl += u;
  }
  if (lane == 63) wsum[wid] = incl;
  __syncthreads();
  int woff = 0;
  for (int w2 = 0; w2 < wid; ++w2) woff += wsum[w2];
  incl += woff;
  if (t < 800) {
    const int excl = incl - val;          // LOCAL edge offset
    const int p0 = excl, p1 = p0 + c0;
    offs[nb + 2 * t] = eb + p0;     rend[nb + 2 * t] = eb + p1;
    offs[nb + 2 * t + 1] = eb + p1; rend[nb + 2 * t + 1] = eb + p1 + c1;
    dis[nb + 2 * t] = rsqrtf((float)c0 + 1.0f);
    dis[nb + 2 * t + 1] = rsqrtf((float)c1 + 1.0f);
    hist[2 * t] = p0;          // reuse as LOCAL cursor
    hist[2 * t + 1] = p1;
  }
  __syncthreads();
  for (int e = t; e < EPG_; e += 1024) {
    const int s = esrc[eb + e];
    const int d = edst[eb + e] - nb;
    const int p = atomicAdd(&hist[d], 1);
    csrs[p] = (unsigned short)(s - nb);
  }
  __syncthreads();
  // coalesced copy-out: 6400 x uint4 (8 u16 each)
  const uint4* s4 = reinterpret_cast<const uint4*>(csrs);
  uint4* d4 = reinterpret_cast<uint4*>(csr + eb);
  for (int i = t; i < EPG_ / 8; i += 1024) d4[i] = s4[i];
}

// ---------------------------------------------------------------------------
// K2: hd = (x @ W1) * dis via MFMA 16x16x32_f16 with fp16 2-SPLIT.
// Seven VALU variants all hit a structural wall (~117-140us): no-shuffle =>
// thread-per-row => 2KB lane stride => L1 amplification at high occupancy
// (r6: FETCH 793MB) vs latency-bound at low occupancy (r1-r5,r7).  MFMA is
// the only shape with cross-lane dot + coalesced A-loads + zero per-row W
// cost.  Numerics: x = a1+a2, W = w1+w2 (RNE fp16 splits, residual exact);
// 3 passes a1w1+a1w2+a2w1 -> h1 err ~7e-7 (dropped terms <= 2^-22 rel).
// Layout (HW-verified, m89): A row=lane&15, k=(lane>>4)*8+j; B col=lane&15;
// D col=lane&15, row=(lane>>4)*4+reg.  One 16-row tile per wave, 6400 waves;
// W pre-split to LDS transposed [2][16][520] halfs -> B frag = 1 ds_read_b128.
// No barriers / no shuffles in main loop; 25 waves/CU scheduled -> HBM-bound.
// ---------------------------------------------------------------------------
typedef _Float16 f16x8 __attribute__((ext_vector_type(8)));
typedef float f32x4 __attribute__((ext_vector_type(4)));
#define WSTR_ 520   // halfs per n-row (512 + 8 pad)

__global__ __launch_bounds__(256, 2) void k_xw1(const float* __restrict__ x,
                                                const float* __restrict__ W1,
                                                const float* __restrict__ dis,
                                                float* __restrict__ hd) {
  __shared__ _Float16 wls[2][16][WSTR_];          // 33,280 B
  const int t = threadIdx.x;

  // stage + split W1 ([512][16] fp32 row-major) -> wls[split][n][k]
  for (int i = t; i < FIN_ * 16; i += 256) {
    const int k = i >> 4, n = i & 15;
    const float w = W1[i];
    const _Float16 w1 = (_Float16)w;
    const float r = w - (float)w1;                // exact (Sterbenz)
    wls[0][n][k] = w1;
    wls[1][n][k] = (_Float16)r;
  }
  __syncthreads();

  const int lane = t & 63, wid = t >> 6;
  const int g = lane >> 4, m = lane & 15;         // m: A-row / B-col / D-col
  const int tile = blockIdx.x * 4 + wid;          // grid 1600 -> 6400 tiles
  const int rb = tile * 16;

  const float* xrow = x + (size_t)(rb + m) * FIN_ + g * 8;
  const _Float16* wb1 = &wls[0][m][g * 8];
  const _Float16* wb2 = &wls[1][m][g * 8];

  f32x4 acc = {0.f, 0.f, 0.f, 0.f};
#pragma unroll
  for (int t4 = 0; t4 < 16; ++t4) {
    const float4 p0 = *reinterpret_cast<const float4*>(xrow + t4 * 32);
    const float4 p1 = *reinterpret_cast<const float4*>(xrow + t4 * 32 + 4);
    const float xv[8] = {p0.x, p0.y, p0.z, p0.w, p1.x, p1.y, p1.z, p1.w};
    f16x8 a1, a2;
#pragma unroll
    for (int j = 0; j < 8; ++j) {
      const _Float16 h = (_Float16)xv[j];
      a1[j] = h;
      a2[j] = (_Float16)(xv[j] - (float)h);       // residual split (exact sub)
    }
    const f16x8 b1 = *reinterpret_cast<const f16x8*>(wb1 + t4 * 32);
    const f16x8 b2 = *reinterpret_cast<const f16x8*>(wb2 + t4 * 32);
    acc = __builtin_amdgcn_mfma_f32_16x16x32_f16(a1, b1, acc, 0, 0, 0);
    acc = __builtin_amdgcn_mfma_f32_16x16x32_f16(a1, b2, acc, 0, 0, 0);
    acc = __builtin_amdgcn_mfma_f32_16x16x32_f16(a2, b1, acc, 0, 0, 0);
  }

  // D: col = m, row = rb + g*4 + reg; stores = 4 full 64B lines each
  const float4 d4 = reinterpret_cast<const float4*>(dis)[(rb >> 2) + g];
  const float dd[4] = {d4.x, d4.y, d4.z, d4.w};
#pragma unroll
  for (int rg = 0; rg < 4; ++rg)
    hd[(size_t)(rb + g * 4 + rg) * 16 + m] = acc[rg] * dd[rg];
}

// ---------------------------------------------------------------------------
// K3: conv1 gather, LDS-staged (per-graph hd slice = 102.4 KB in LDS).
// ---------------------------------------------------------------------------
__global__ __launch_bounds__(1024) void k_conv1l(
    const unsigned short* __restrict__ csr, const int* __restrict__ offs,
    const int* __restrict__ rend, const float* __restrict__ hd,
    const float* __restrict__ dis, const float* __restrict__ b1,
    const float* __restrict__ Wrel, const float* __restrict__ Wroot,
    float* __restrict__ h1, float* __restrict__ rarr, float* __restrict__ tarr) {
  __shared__ float hds[NPG_ * 16];                // 102,400 B
  const int g = blockIdx.x >> 2, q = blockIdx.x & 3;
  const int nb = g * NPG_;
  const int t = threadIdx.x;
  {
    const float4* src = reinterpret_cast<const float4*>(hd + (size_t)nb * 16);
    float4* dst = reinterpret_cast<float4*>(hds);
    for (int i = t; i < NPG_ * 4; i += 1024) dst[i] = src[i];
  }
  __syncthreads();
  const int c = t & 15;
  const float bb = b1[c], wr = Wrel[c], wo = Wroot[c];
  const int vend = q * 400 + 400;
  for (int vl = q * 400 + (t >> 4); vl < vend; vl += 64) {
    const int v = nb + vl;
    const int rs = offs[v], re = rend[v];
    float acc = 0.f;
    int k = rs;
    for (; k + 4 <= re; k += 4) {
      const int s0 = csr[k], s1 = csr[k + 1];
      const int s2 = csr[k + 2], s3 = csr[k + 3];
      acc += hds[s0 * 16 + c] + hds[s1 * 16 + c];
      acc += hds[s2 * 16 + c] + hds[s3 * 16 + c];
    }
    for (; k < re; ++k) acc += hds[csr[k] * 16 + c];
    const float dd = dis[v];
    float val = fmaf(acc + hds[vl * 16 + c], dd, bb);
    val = fmaxf(val, 0.f);
    h1[(size_t)v * 16 + c] = val;
    float r = val * wr;
    float tt = val * wo;
#pragma unroll
    for (int m = 1; m < 16; m <<= 1) {
      r += __shfl_xor(r, m);
      tt += __shfl_xor(tt, m);
    }
    if (c == 0) { rarr[v] = r; tarr[v] = tt; }
  }
}

// ---------------------------------------------------------------------------
// K4: per-graph fused score + radix-select top-K + filtered degree + h1w.
// Scans are shuffle-based.
// ---------------------------------------------------------------------------
__global__ __launch_bounds__(1024) void k_scoretopk(
    const unsigned short* __restrict__ csr, const int* __restrict__ offs,
    const int* __restrict__ rend, const float* __restrict__ rarr,
    const float* __restrict__ tarr, const float* __restrict__ brel,
    const float* __restrict__ h1, int* __restrict__ kept,
    float* __restrict__ dis2, float* __restrict__ h1w,
    float* __restrict__ out) {
  __shared__ float rar[NPG_];
  __shared__ float sar[NPG_];       // tarr, then score
  __shared__ int   ofs[NPG_];
  __shared__ int   ren[NPG_];
  __shared__ unsigned uu[NPG_];     // monotone keys
  __shared__ int   kp[NPG_];
  __shared__ float wv[NPG_];
  __shared__ int   hist[256];
  __shared__ int   part[16];        // per-wave scan sums
  __shared__ int   scal[2];         // lo, rem

  const int g = blockIdx.x, t = threadIdx.x;
  const int lane = t & 63, wid = t >> 6;
  const int nb = g * NPG_;

  // P0: stage
  for (int i = t; i < NPG_; i += 1024) {
    rar[i] = rarr[nb + i];
    sar[i] = tarr[nb + i];
    ofs[i] = offs[nb + i];
    ren[i] = rend[nb + i];
  }
  if (t == 0) { scal[0] = 0; scal[1] = KEEP_; }
  __syncthreads();

  // P1: score = tanh(sum rar[neighbors] + brel + tarr)
  const float br = brel[0];
  for (int v = t; v < NPG_; v += 1024) {
    const int rs = ofs[v], re = ren[v];
    float sum = 0.f;
    int k = rs;
    for (; k + 4 <= re; k += 4) {
      sum += rar[csr[k]] + rar[csr[k + 1]];
      sum += rar[csr[k + 2]] + rar[csr[k + 3]];
    }
    for (; k < re; ++k) sum += rar[csr[k]];
    const float s = tanhf(sum + br + sar[v]);
    sar[v] = s;
    const unsigned ub = __float_as_uint(s);
    uu[v] = (ub & 0x80000000u) ? ~ub : (ub | 0x80000000u);
  }
  __syncthreads();

  // P2: radix select (4 passes of 8 bits, MSB first)
  const unsigned maskTab[4] = {0u, 0xFF000000u, 0xFFFF0000u, 0xFFFFFF00u};
  const int shTab[4] = {24, 16, 8, 0};
  for (int pass = 0; pass < 4; ++pass) {
    const unsigned lo = (unsigned)scal[0];
    const int remc = scal[1];
    const unsigned msk = maskTab[pass];
    const int sh = shTab[pass];
    if (t < 256) hist[t] = 0;
    __syncthreads();
    for (int v = t; v < NPG_; v += 1024) {
      const unsigned u = uu[v];
      if (((u ^ lo) & msk) == 0) atomicAdd(&hist[(u >> sh) & 255], 1);
    }
    __syncthreads();
    int hv = 0;
    if (t < 256) hv = hist[t];
    int incl = hv;
#pragma unroll
    for (int m = 1; m < 64; m <<= 1) {
      const int u2 = __shfl_up(incl, m);
      if (lane >= m) incl += u2;
    }
    if (t < 256 && lane == 63) part[wid] = incl;  // waves 0..3
    __syncthreads();
    if (t < 256) {
      int woff = 0;
      for (int w2 = 0; w2 < wid; ++w2) woff += part[w2];
      const int tot = part[0] + part[1] + part[2] + part[3];
      const int sb = tot - (incl + woff) + hv;    // suffix sum from bin t
      const int sb1 = sb - hv;                    // suffix sum from bin t+1
      if (sb >= remc && sb1 < remc) {             // unique boundary bin
        scal[0] = (int)(lo | ((unsigned)t << sh));
        scal[1] = remc - sb1;
      }
    }
    __syncthreads();
  }
  const unsigned T = (unsigned)scal[0];
  const int remT = scal[1];

  // tie-break by index: keep first remT nodes with key == T (shuffle scan)
  const int i0 = 2 * t, i1 = 2 * t + 1;
  int f0 = 0, f1 = 0;
  if (i0 < NPG_) f0 = (uu[i0] == T);
  if (i1 < NPG_) f1 = (uu[i1] == T);
  int incl2 = f0 + f1;
#pragma unroll
  for (int m = 1; m < 64; m <<= 1) {
    const int u2 = __shfl_up(incl2, m);
    if (lane >= m) incl2 += u2;
  }
  if (lane == 63) part[wid] = incl2;
  __syncthreads();
  int woff2 = 0;
  for (int w2 = 0; w2 < wid; ++w2) woff2 += part[w2];
  const int excl = incl2 + woff2 - (f0 + f1);
  if (i0 < NPG_) kp[i0] = (uu[i0] > T) || (f0 && excl < remT);
  if (i1 < NPG_) kp[i1] = (uu[i1] > T) || (f1 && (excl + f0) < remT);
  __syncthreads();
  for (int v = t; v < NPG_; v += 1024) kept[nb + v] = kp[v];

  // P3: filtered degree -> dis2, wv = score * dis2 (0 for dropped)
  for (int v = t; v < NPG_; v += 1024) {
    float w = 0.f;
    if (kp[v]) {
      const int rs = ofs[v], re = ren[v];
      int c2 = 0, k = rs;
      for (; k + 4 <= re; k += 4) {
        c2 += kp[csr[k]] + kp[csr[k + 1]];
        c2 += kp[csr[k + 2]] + kp[csr[k + 3]];
      }
      for (; k < re; ++k) c2 += kp[csr[k]];
      const float d2 = rsqrtf((float)c2 + 1.0f);
      dis2[nb + v] = d2;
      w = sar[v] * d2;
    }
    wv[v] = w;
  }
  // zero the output slice for this graph
  if (t < HOUT_) out[g * HOUT_ + t] = 0.f;
  __syncthreads();

  // P4: h1w = h1 * wv[v]
  for (int i = t; i < NPG_ * 16; i += 1024)
    h1w[(size_t)nb * 16 + i] = h1[(size_t)nb * 16 + i] * wv[i >> 4];
}

// ---------------------------------------------------------------------------
// K5: conv2 gather, LDS-staged (same structure as K3).
// ---------------------------------------------------------------------------
__global__ __launch_bounds__(1024) void k_conv2l(
    const unsigned short* __restrict__ csr, const int* __restrict__ offs,
    const int* __restrict__ rend, const float* __restrict__ h1w,
    const int* __restrict__ kept, const float* __restrict__ dis2,
    float* __restrict__ y16) {
  __shared__ float hds[NPG_ * 16];                // 102,400 B
  const int g = blockIdx.x >> 2, q = blockIdx.x & 3;
  const int nb = g * NPG_;
  const int t = threadIdx.x;
  {
    const float4* src = reinterpret_cast<const float4*>(h1w + (size_t)nb * 16);
    float4* dst = reinterpret_cast<float4*>(hds);
    for (int i = t; i < NPG_ * 4; i += 1024) dst[i] = src[i];
  }
  __syncthreads();
  const int c = t & 15;
  const int vend = q * 400 + 400;
  for (int vl = q * 400 + (t >> 4); vl < vend; vl += 64) {
    const int v = nb + vl;
    if (!kept[v]) continue;                       // uniform per 16-group
    const int rs = offs[v], re = rend[v];
    float acc = 0.f;
    int k = rs;
    for (; k + 4 <= re; k += 4) {
      const int s0 = csr[k], s1 = csr[k + 1];
      const int s2 = csr[k + 2], s3 = csr[k + 3];
      acc += hds[s0 * 16 + c] + hds[s1 * 16 + c];
      acc += hds[s2 * 16 + c] + hds[s3 * 16 + c];
    }
    for (; k < re; ++k) acc += hds[csr[k] * 16 + c];
    acc += hds[vl * 16 + c];                      // self loop
    y16[(size_t)v * 16 + c] = acc * dis2[v];
  }
}

// ---------------------------------------------------------------------------
// K6: out[g] += relu(y16[v]@W2 + b2)/K  fused GEMM+ReLU+mean-pool.
// ---------------------------------------------------------------------------
__global__ __launch_bounds__(256, 1) void k_gemm2pool(const float* __restrict__ y16,
                                                      const int* __restrict__ kept,
                                                      const float* __restrict__ W2,
                                                      const float* __restrict__ b2,
                                                      float* __restrict__ out) {
  __shared__ float red[256];
  const int blk = blockIdx.x;                     // grid 2048
  const int g = blk >> 5;
  const int sub = blk & 31;
  const int jbase = (sub & 1) * 256;
  const int nstart = g * NPG_ + (sub >> 1) * 100;
  const int tid = threadIdx.x;
  const int wave = tid >> 6, lane = tid & 63;

  float w[16][4];
#pragma unroll
  for (int k = 0; k < 16; ++k)
#pragma unroll
    for (int c = 0; c < 4; ++c)
      w[k][c] = W2[k * HOUT_ + jbase + lane + c * 64];
  float b2r[4];
#pragma unroll
  for (int c = 0; c < 4; ++c) b2r[c] = b2[jbase + lane + c * 64];

  float acc[4] = {0.f, 0.f, 0.f, 0.f};
  for (int i = wave; i < 100; i += 4) {
    const int v = nstart + i;
    if (!kept[v]) continue;                       // wave-uniform
    const float4* yp = reinterpret_cast<const float4*>(y16 + (size_t)v * 16);
    float4 q0 = yp[0], q1 = yp[1], q2 = yp[2], q3 = yp[3];
    const float yv[16] = {q0.x, q0.y, q0.z, q0.w, q1.x, q1.y, q1.z, q1.w,
                          q2.x, q2.y, q2.z, q2.w, q3.x, q3.y, q3.z, q3.w};
    float z[4] = {b2r[0], b2r[1], b2r[2], b2r[3]};
#pragma unroll
    for (int k = 0; k < 16; ++k)
#pragma unroll
      for (int c = 0; c < 4; ++c)
        z[c] = fmaf(yv[k], w[k][c], z[c]);
#pragma unroll
    for (int c = 0; c < 4; ++c) acc[c] += fmaxf(z[c], 0.f);
  }

  red[tid] = 0.f;
  __syncthreads();
#pragma unroll
  for (int c = 0; c < 4; ++c) atomicAdd(&red[lane + 64 * c], acc[c]);
  __syncthreads();
  atomicAdd(&out[g * HOUT_ + jbase + tid], red[tid] * (1.0f / (float)KEEP_));
}

// ---------------------------------------------------------------------------
extern "C" void kernel_launch(void* const* d_in, const int* in_sizes, int n_in,
                              void* d_out, int out_size, void* d_ws, size_t ws_size,
                              hipStream_t stream) {
  (void)in_sizes; (void)n_in; (void)out_size; (void)ws_size;
  const float* x     = (const float*)d_in[0];
  const int*   ei    = (const int*)  d_in[1];
  const float* W1    = (const float*)d_in[3];
  const float* b1    = (const float*)d_in[4];
  const float* Wrel  = (const float*)d_in[5];
  const float* brel  = (const float*)d_in[6];
  const float* Wroot = (const float*)d_in[7];
  const float* W2    = (const float*)d_in[8];
  const float* b2    = (const float*)d_in[9];
  const int* esrc = ei;
  const int* edst = ei + E_;

  // slab quarters: hd / h1 / h1w / y16
  char* ws = (char*)d_ws;
  float*          hd    = (float*)(ws);                    // q0: 6,553,600 B
  float*          h1    = (float*)(ws + 6553600);          // q1
  float*          h1w   = (float*)(ws + 13107200);         // q2
  float*          y16   = (float*)(ws + 19660800);         // q3
  unsigned short* csr   = (unsigned short*)(ws + 26214400);// 6,553,600 B
  int*            offs  = (int*)(ws + 32768000);
  int*            rendp = (int*)(ws + 33177600);
  float*          dis   = (float*)(ws + 33587200);
  int*            kept  = (int*)(ws + 33996800);
  float*          rarr  = (float*)(ws + 34406400);
  float*          tarr  = (float*)(ws + 34816000);
  float*          dis2  = (float*)(ws + 35225600);
  float*          out   = (float*)d_out;

  hipLaunchKernelGGL(k_build,     dim3(G_),    dim3(1024), 0, stream,
                     esrc, edst, offs, rendp, dis, csr);
  hipLaunchKernelGGL(k_xw1,       dim3(1600),  dim3(256),  0, stream,
                     x, W1, dis, hd);
  hipLaunchKernelGGL(k_conv1l,    dim3(256),   dim3(1024), 0, stream,
                     csr, offs, rendp, hd, dis, b1, Wrel, Wroot, h1, rarr, tarr);
  hipLaunchKernelGGL(k_scoretopk, dim3(G_),    dim3(1024), 0, stream,
                     csr, offs, rendp, rarr, tarr, brel, h1, kept, dis2, h1w, out);
  hipLaunchKernelGGL(k_conv2l,    dim3(256),   dim3(1024), 0, stream,
                     csr, offs, rendp, h1w, kept, dis2, y16);
  hipLaunchKernelGGL(k_gemm2pool, dim3(2048),  dim3(256),  0, stream,
                     y16, kept, W2, b2, out);
}